// Round 3
// baseline (239.547 us; speedup 1.0000x reference)
//
#include <hip/hip_runtime.h>

#define N_Q   65536
#define N_C   2048
#define KNN_K 16
#define CDIM  64
#define SLCAP 128
#define KINF  0x7FFFFFFF
#define WSZ   108544  // halves per weight image

typedef _Float16 half_t;
typedef float v4f __attribute__((ext_vector_type(4)));
typedef half_t v8h __attribute__((ext_vector_type(8)));

#define ASTRIDE 136   // 128 + 8 pad (halves); row = 272 B = 17*16 B
#define DSTRIDE 40    // 32 + 8 pad

// ---------------------------------------------------------------------------
// DPP lane-xor for the serially dependent bitonic chains (unchanged).
// ---------------------------------------------------------------------------
__device__ __forceinline__ int dppx(int v, int j){
  if (j == 1) return __builtin_amdgcn_mov_dpp(v, 0xB1,  0xF, 0xF, true); // quad_perm [1,0,3,2]
  if (j == 2) return __builtin_amdgcn_mov_dpp(v, 0x4E,  0xF, 0xF, true); // quad_perm [2,3,0,1]
  if (j == 8) return __builtin_amdgcn_mov_dpp(v, 0x128, 0xF, 0xF, true); // row_ror:8
  return __shfl_xor(v, j, 64);
}
__device__ __forceinline__ float dppxf(float v, int j){
  return __int_as_float(dppx(__float_as_int(v), j));
}

// ---------------------------------------------------------------------------
// Kernel 0: weights -> fp16 MFMA-fragment-order tiles + cpos4 (unchanged)
// ---------------------------------------------------------------------------
__global__ void wtrans_kernel(const float* W0, const float* W1, const float* W2,
                              const float* W3, const float* Wf, const float* Wd,
                              const int* indices, const float* cpos,
                              half_t* wt, float4* cpos4){
  int idx = blockIdx.x * 256 + threadIdx.x;
  if (idx >= 110592) return;
  if (idx >= WSZ){
    int i = idx - WSZ;
    const float* cp = cpos + (size_t)indices[0] * N_C * 3;
    float x = cp[i*3 + 0], y = cp[i*3 + 1], z = cp[i*3 + 2];
    cpos4[i] = make_float4(x, y, z, fmaf(x, x, fmaf(y, y, fmaf(z, z, 4.0f))));
    return;
  }
  int base, nt, mode;            // mode: 0 plain(src), 1 W0, 2 W2, 3 Wd
  const float* src = W1;
  if (idx < 16384){ base = 0; nt = 8; mode = 1; }
  else if (idx < 32768){ base = 16384; nt = 8; mode = 0; src = W1; }
  else if (idx < 65536){ base = 32768; nt = 8; mode = 2; }
  else if (idx < 81920){ base = 65536; nt = 8; mode = 0; src = W3; }
  else if (idx < 98304){ base = 81920; nt = 8; mode = 0; src = Wf; }
  else { base = 98304; nt = 4; mode = 3; }
  int i = idx - base;
  int tile = i >> 9, e = i & 511;
  int lane = e >> 3, j = e & 7;
  int k0idx = tile / nt, tcol = tile - k0idx*nt;
  int n = tcol*16 + (lane & 15);
  int k = k0idx*32 + ((lane >> 4) << 3) + j;
  float val;
  if (mode == 0)      val = src[k*128 + n];
  else if (mode == 1) val = (k < 127) ? W0[k*128 + n] : 0.f;
  else if (mode == 2) val = (k == 127) ? 0.f
                           : ((k < 127) ? W2[k*128 + n] : W2[(k-1)*128 + n]);
  else                val = (k < 155) ? Wd[k*64 + n] : 0.f;
  wt[idx] = (half_t)val;
}

// ---------------------------------------------------------------------------
// Kernel 1: exact 16-NN + activation staging (unchanged from round 2).
// ---------------------------------------------------------------------------
__global__ __launch_bounds__(512, 6) void knn_kernel(const int* indices,
    const float* qpts, const float4* cpos4, const float* codes,
    const float* xyzdir, half_t* Ain, half_t* Din){
  __shared__ float4 lp[N_C];        // 32 KB
  __shared__ int    sl[8*SLCAP];    // 4 KB
  int tid = threadIdx.x;
  int lane = tid & 63, wave = tid >> 6;
  int l = lane & 15;                // lane within 16-group
  const float* cc = codes + (size_t)indices[0] * N_C * CDIM;

  for (int c = tid; c < N_C; c += 512) lp[c] = cpos4[c];
  __syncthreads();

  int q = blockIdx.x * 8 + wave;
  float qx = qpts[q*3 + 0];
  float qy = qpts[q*3 + 1];
  float qz = qpts[q*3 + 2];
  float nqx = -2.0f*qx, nqy = -2.0f*qy, nqz = -2.0f*qz;

  int p[32];
#pragma unroll
  for (int j = 0; j < 32; j++){
    int c = j*64 + lane;
    float4 P = lp[c];
    float s = fmaf(P.x, nqx, fmaf(P.y, nqy, fmaf(P.z, nqz, P.w)));  // > 0
    int pv = (__float_as_int(s) & 0xFFFFF800) | c;
    asm("" : "+v"(pv));   // opaque def: cannot be rematerialized from LDS
    p[j] = pv;
  }

  int lm = p[0];
#pragma unroll
  for (int j = 1; j < 32; j++) lm = min(lm, p[j]);

  int v = lm;
#pragma unroll
  for (int k = 2; k <= 16; k <<= 1){
#pragma unroll
    for (int j = k >> 1; j > 0; j >>= 1){
      int o = dppx(v, j);
      bool dirDesc = (l & k) != 0;
      bool lower   = (l & j) == 0;
      int mn = min(v, o), mx = max(v, o);
      v = (lower != dirDesc) ? mn : mx;
    }
  }
  int t0 = __shfl(v, 3, 64),  t1 = __shfl(v, 19, 64);
  int t2 = __shfl(v, 35, 64), t3 = __shfl(v, 51, 64);
  int tau = max(max(t0, t1), max(t2, t3));

  int* slw = &sl[wave * SLCAP];
  int n = 0;
#pragma unroll
  for (int j = 0; j < 32; j++){
    bool c = (p[j] <= tau);
    unsigned long long m = __ballot(c);
    if (m){
      if (n <= 64){
        if (c){
          int mb = __builtin_amdgcn_mbcnt_hi((unsigned)(m >> 32),
                   __builtin_amdgcn_mbcnt_lo((unsigned)m, 0));
          slw[n + mb] = p[j];
        }
      }
      n += (int)__popcll(m);
    }
  }
  __builtin_amdgcn_wave_barrier();

  int keep;
  if (n >= KNN_K && n <= 64){
    int x = (lane < n) ? slw[lane] : KINF;
#pragma unroll
    for (int k = 2; k <= 16; k <<= 1){
#pragma unroll
      for (int j = k >> 1; j > 0; j >>= 1){
        int o = dppx(x, j);
        bool dirDesc = (l & k) != 0;
        bool lower   = (l & j) == 0;
        int mn = min(x, o), mx = max(x, o);
        x = (lower != dirDesc) ? mn : mx;
      }
    }
    x = min(x, __shfl_xor(x, 31, 64));
#pragma unroll
    for (int j = 8; j > 0; j >>= 1){
      int o = dppx(x, j);
      bool lower = (l & j) == 0;
      int mn = min(x, o), mx = max(x, o);
      x = lower ? mn : mx;
    }
    x = min(x, __shfl_xor(x, 63, 64));
    keep = x;
  } else {
    keep = KINF;
#pragma unroll 1
    for (int rr = 0; rr < KNN_K; rr++){
      int lmf = p[0];
#pragma unroll
      for (int j = 1; j < 32; j++) lmf = min(lmf, p[j]);
      int gm = lmf;
#pragma unroll
      for (int off2 = 1; off2 < 64; off2 <<= 1)
        gm = min(gm, __shfl_xor(gm, off2, 64));
      if (lane == rr) keep = gm;
#pragma unroll
      for (int j = 0; j < 32; j++) p[j] = (p[j] == gm) ? KINF : p[j];
    }
  }

  int ci = keep & 0x7FF;
  float4 P = lp[ci];
  float dx = qx - P.x, dy = qy - P.y, dz = qz - P.z;
  float d2 = fmaf(dz, dz, fmaf(dy, dy, dx*dx));
  float w = 1.0f / (d2 + 1e-16f);
  float wm = (lane < KNN_K) ? w : 0.0f;
  wm += dppxf(wm, 1);
  wm += dppxf(wm, 2);
  wm += __shfl_xor(wm, 4, 64);
  wm += dppxf(wm, 8);
  float wn = w / wm;

  float acc = 0.f;
#pragma unroll
  for (int i = 0; i < KNN_K; i++){
    int   cb = __shfl(ci, i, 64);
    float wb = __shfl(wn, i, 64);
    acc = fmaf(wb, cc[cb*CDIM + lane], acc);
  }
  size_t arow = (size_t)q * ASTRIDE;
  Ain[arow + lane] = (half_t)acc;

  float xv = (lane < 63) ? xyzdir[(size_t)q*90 + lane] : 0.f;
  Ain[arow + 64 + lane] = (half_t)xv;
  if (lane < 8) Ain[arow + 128 + lane] = (half_t)0.f;
  if (lane < 40){
    float dv = (lane < 27) ? xyzdir[(size_t)q*90 + 63 + lane] : 0.f;
    Din[(size_t)q*DSTRIDE + lane] = (half_t)dv;
  }
}

// ---------------------------------------------------------------------------
// Kernel 2 (R18 REWRITE): barrier-free wave-private MLP. One wave owns 16
// queries end-to-end; inter-layer transposes via wave-private LDS tiles
// (same-wave ds_write->ds_read ordering, NO __syncthreads). Old structure
// was 7 barriers x 8 waves per block with only ~16 MFMAs/wave/phase ->
// every phase stalled on the slowest L2 weight load (~6% MFMA util).
// LDS: 4 waves x (2x4352 + 1280) = 39,936 B -> exactly 4 blocks/CU.
// ---------------------------------------------------------------------------
template<int KC, int NT>
__device__ __forceinline__ void wave_layer(const half_t* inb, int istride,
                                           const half_t* wlayer, int nt_total,
                                           int ktbase, v4f acc[NT], int lane){
  int m = lane & 15, quad = lane >> 4;
  v8h areg[KC];
#pragma unroll
  for (int c = 0; c < KC; c++)
    areg[c] = *(const v8h*)&inb[m*istride + (c << 5) + (quad << 3)];
#pragma unroll
  for (int c = 0; c < KC; c++){
#pragma unroll
    for (int t = 0; t < NT; t++){
      const half_t* bp = wlayer +
          ((size_t)(((ktbase + c)*nt_total + t) << 9) + (lane << 3));
      v8h b = *(const v8h*)bp;
      acc[t] = __builtin_amdgcn_mfma_f32_16x16x32_f16(areg[c], b, acc[t], 0, 0, 0);
    }
  }
}

template<int NT>
__device__ __forceinline__ void wave_epi(v4f acc[NT], half_t* outb, int ostride,
                                         const float* bias, bool relu, int lane){
  int m16 = lane & 15, quad = lane >> 4;
#pragma unroll
  for (int t = 0; t < NT; t++){
    int col = t*16 + m16;
    float bv = bias[col];
#pragma unroll
    for (int r = 0; r < 4; r++){
      float v = acc[t][r] + bv;
      if (relu) v = fmaxf(v, 0.f);
      outb[(quad*4 + r)*ostride + col] = (half_t)v;
    }
  }
}

__global__ __launch_bounds__(256, 4) void mlp_mfma(
    const half_t* Ain, const half_t* Din, const half_t* wt,
    const float* b0, const float* b1, const float* b2, const float* b3,
    const float* bfb, const float* bdb,
    const float* Wsb, const float* bsb, const float* Wrb, const float* brb,
    float* out){
  __shared__ __align__(16) half_t bufA[4][16*ASTRIDE];   // 17,408 B
  __shared__ __align__(16) half_t bufB[4][16*ASTRIDE];   // 17,408 B
  __shared__ __align__(16) half_t bufD[4][16*DSTRIDE];   //  5,120 B

  int tid = threadIdx.x, lane = tid & 63, wave = tid >> 6;
  int qbase = (blockIdx.x * 4 + wave) * 16;

  half_t* A = bufA[wave];
  half_t* B = bufB[wave];
  half_t* D = bufD[wave];

  // Stage this wave's 16 activation rows (wave-private; no barrier).
  for (int i = lane; i < 16*17; i += 64){
    int r = i / 17, c8 = i - r*17;
    *(uint4*)&A[r*ASTRIDE + (c8 << 3)] =
        *(const uint4*)&Ain[(size_t)(qbase + r)*ASTRIDE + (c8 << 3)];
  }
  for (int i = lane; i < 16*5; i += 64){
    int r = i / 5, c8 = i - r*5;
    *(uint4*)&D[r*DSTRIDE + (c8 << 3)] =
        *(const uint4*)&Din[(size_t)(qbase + r)*DSTRIDE + (c8 << 3)];
  }

  const half_t* wt0 = wt;
  const half_t* wt1 = wt + 16384;
  const half_t* wt2 = wt + 32768;
  const half_t* wt3 = wt + 65536;
  const half_t* wtf = wt + 81920;
  const half_t* wtd = wt + 98304;

  v4f acc[8];
#define ZACC8() { _Pragma("unroll") for (int t_ = 0; t_ < 8; t_++) \
                  _Pragma("unroll") for (int e_ = 0; e_ < 4; e_++) acc[t_][e_] = 0.f; }

  // L0: A @ W0 -> B (relu)
  ZACC8();
  wave_layer<4,8>(A, ASTRIDE, wt0, 8, 0, acc, lane);
  wave_epi<8>(acc, B, ASTRIDE, b0, true, lane);

  // L1: B(h0) @ W1 -> B in-place (h1): all reads precede writes in-wave.
  ZACC8();
  wave_layer<4,8>(B, ASTRIDE, wt1, 8, 0, acc, lane);
  wave_epi<8>(acc, B, ASTRIDE, b1, true, lane);

  // L2: [A | B(h1)] @ W2 (K=256) -> B in-place (h2)
  ZACC8();
  wave_layer<4,8>(A, ASTRIDE, wt2, 8, 0, acc, lane);
  wave_layer<4,8>(B, ASTRIDE, wt2, 8, 4, acc, lane);
  wave_epi<8>(acc, B, ASTRIDE, b2, true, lane);

  // L3: B(h2) @ W3 -> B in-place (h3)
  ZACC8();
  wave_layer<4,8>(B, ASTRIDE, wt3, 8, 0, acc, lane);
  wave_epi<8>(acc, B, ASTRIDE, b3, true, lane);

  // Wf: B(h3) @ Wf -> A (final; A's original content dead after L2)
  ZACC8();
  wave_layer<4,8>(B, ASTRIDE, wtf, 8, 0, acc, lane);
  wave_epi<8>(acc, A, ASTRIDE, bfb, false, lane);

  // sigma = h3 . Ws  (read B BEFORE Wd's epilogue overwrites it)
  int m16 = lane & 15, quad = lane >> 4;
  float sig;
  {
    float s = 0.f;
#pragma unroll
    for (int i = 0; i < 4; i++){
      v8h hv = *(const v8h*)&B[m16*ASTRIDE + quad*32 + i*8];
      float4 w0 = *(const float4*)&Wsb[quad*32 + i*8];
      float4 w1 = *(const float4*)&Wsb[quad*32 + i*8 + 4];
      s = fmaf((float)hv[0], w0.x, s); s = fmaf((float)hv[1], w0.y, s);
      s = fmaf((float)hv[2], w0.z, s); s = fmaf((float)hv[3], w0.w, s);
      s = fmaf((float)hv[4], w1.x, s); s = fmaf((float)hv[5], w1.y, s);
      s = fmaf((float)hv[6], w1.z, s); s = fmaf((float)hv[7], w1.w, s);
    }
    s += __shfl_xor(s, 16, 64);
    s += __shfl_xor(s, 32, 64);
    sig = s;
  }

  // Wd: [A(final) | D(dir)] @ Wd (K=160, N=64) -> B[:,0:64] (relu)
  v4f accd[4];
#pragma unroll
  for (int t_ = 0; t_ < 4; t_++)
#pragma unroll
    for (int e_ = 0; e_ < 4; e_++) accd[t_][e_] = 0.f;
  wave_layer<4,4>(A, ASTRIDE, wtd, 4, 0, accd, lane);
  wave_layer<1,4>(D, DSTRIDE, wtd, 4, 4, accd, lane);
  wave_epi<4>(accd, B, ASTRIDE, bdb, true, lane);

  // rgb = d . Wr  (d = B[:,0:64])
  {
    float r3[3] = {0.f, 0.f, 0.f};
    v8h d0 = *(const v8h*)&B[m16*ASTRIDE + quad*16];
    v8h d1 = *(const v8h*)&B[m16*ASTRIDE + quad*16 + 8];
#pragma unroll
    for (int c2 = 0; c2 < 3; c2++){
      float rv = 0.f;
#pragma unroll
      for (int k = 0; k < 8; k++){
        rv = fmaf((float)d0[k], Wrb[(quad*16 + k)*3 + c2], rv);
        rv = fmaf((float)d1[k], Wrb[(quad*16 + 8 + k)*3 + c2], rv);
      }
      rv += __shfl_xor(rv, 16, 64);
      rv += __shfl_xor(rv, 32, 64);
      r3[c2] = rv;
    }
    if (quad == 0){
      size_t ob = ((size_t)(qbase + m16)) * 4;
      float4 o4 = make_float4(r3[0] + brb[0], r3[1] + brb[1],
                              r3[2] + brb[2], sig + bsb[0]);
      *(float4*)&out[ob] = o4;
    }
  }
}

// ---------------------------------------------------------------------------
extern "C" void kernel_launch(void* const* d_in, const int* in_sizes, int n_in,
                              void* d_out, int out_size, void* d_ws, size_t ws_size,
                              hipStream_t stream){
  (void)in_sizes; (void)n_in; (void)out_size; (void)ws_size;

  const int*   indices = (const int*)d_in[0];
  const float* qpts    = (const float*)d_in[1];
  const float* xyzdir  = (const float*)d_in[2];
  const float* cpos    = (const float*)d_in[3];
  const float* codes   = (const float*)d_in[4];
  const float* W0 = (const float*)d_in[5];
  const float* b0 = (const float*)d_in[6];
  const float* W1 = (const float*)d_in[7];
  const float* b1 = (const float*)d_in[8];
  const float* W2 = (const float*)d_in[9];
  const float* b2 = (const float*)d_in[10];
  const float* W3 = (const float*)d_in[11];
  const float* b3 = (const float*)d_in[12];
  const float* Wf = (const float*)d_in[13];
  const float* bf = (const float*)d_in[14];
  const float* Wd = (const float*)d_in[15];
  const float* bd = (const float*)d_in[16];
  const float* Ws = (const float*)d_in[17];
  const float* bs = (const float*)d_in[18];
  const float* Wr = (const float*)d_in[19];
  const float* br = (const float*)d_in[20];

  // ws layout (16-B aligned): Ain | Din | wt | cpos4
  half_t* Ain   = (half_t*)d_ws;                                   // 17,825,792 B
  half_t* Din   = (half_t*)((char*)d_ws + 17825792);               //  5,242,880 B
  half_t* wt    = (half_t*)((char*)d_ws + 17825792 + 5242880);     //    217,088 B
  float4* cpos4 = (float4*)((char*)d_ws + 17825792 + 5242880 + 217088);

  wtrans_kernel<<<(110592 + 255)/256, 256, 0, stream>>>(W0, W1, W2, W3, Wf, Wd,
                                                        indices, cpos, wt, cpos4);
  knn_kernel<<<N_Q/8, 512, 0, stream>>>(indices, qpts, cpos4, codes, xyzdir,
                                        Ain, Din);
  mlp_mfma<<<N_Q/64, 256, 0, stream>>>(Ain, Din, wt,
                                       b0, b1, b2, b3, bf, bd, Ws, bs, Wr, br,
                                       (float*)d_out);
}

// Round 4
// 233.820 us; speedup vs baseline: 1.0245x; 1.0245x over previous
//
#include <hip/hip_runtime.h>

#define N_Q   65536
#define N_C   2048
#define KNN_K 16
#define CDIM  64
#define SLCAP 128
#define KINF  0x7FFFFFFF
#define WSZ   108544  // halves per weight image

typedef _Float16 half_t;
typedef float v4f __attribute__((ext_vector_type(4)));
typedef half_t v8h __attribute__((ext_vector_type(8)));

#define ASTRIDE 136   // 128 + 8 pad (halves); row = 272 B = 17*16 B
#define DSTRIDE 40    // 32 + 8 pad

// ---------------------------------------------------------------------------
// DPP lane-xor for the serially dependent bitonic chains.
// ---------------------------------------------------------------------------
__device__ __forceinline__ int dppx(int v, int j){
  if (j == 1) return __builtin_amdgcn_mov_dpp(v, 0xB1,  0xF, 0xF, true); // quad_perm [1,0,3,2]
  if (j == 2) return __builtin_amdgcn_mov_dpp(v, 0x4E,  0xF, 0xF, true); // quad_perm [2,3,0,1]
  if (j == 8) return __builtin_amdgcn_mov_dpp(v, 0x128, 0xF, 0xF, true); // row_ror:8
  return __shfl_xor(v, j, 64);
}
__device__ __forceinline__ float dppxf(float v, int j){
  return __int_as_float(dppx(__float_as_int(v), j));
}

// ---------------------------------------------------------------------------
// Kernel 0: weights -> fp16 MFMA-fragment-order tiles + cpos4 (unchanged)
// ---------------------------------------------------------------------------
__global__ void wtrans_kernel(const float* W0, const float* W1, const float* W2,
                              const float* W3, const float* Wf, const float* Wd,
                              const int* indices, const float* cpos,
                              half_t* wt, float4* cpos4){
  int idx = blockIdx.x * 256 + threadIdx.x;
  if (idx >= 110592) return;
  if (idx >= WSZ){
    int i = idx - WSZ;
    const float* cp = cpos + (size_t)indices[0] * N_C * 3;
    float x = cp[i*3 + 0], y = cp[i*3 + 1], z = cp[i*3 + 2];
    cpos4[i] = make_float4(x, y, z, fmaf(x, x, fmaf(y, y, fmaf(z, z, 4.0f))));
    return;
  }
  int base, nt, mode;            // mode: 0 plain(src), 1 W0, 2 W2, 3 Wd
  const float* src = W1;
  if (idx < 16384){ base = 0; nt = 8; mode = 1; }
  else if (idx < 32768){ base = 16384; nt = 8; mode = 0; src = W1; }
  else if (idx < 65536){ base = 32768; nt = 8; mode = 2; }
  else if (idx < 81920){ base = 65536; nt = 8; mode = 0; src = W3; }
  else if (idx < 98304){ base = 81920; nt = 8; mode = 0; src = Wf; }
  else { base = 98304; nt = 4; mode = 3; }
  int i = idx - base;
  int tile = i >> 9, e = i & 511;
  int lane = e >> 3, j = e & 7;
  int k0idx = tile / nt, tcol = tile - k0idx*nt;
  int n = tcol*16 + (lane & 15);
  int k = k0idx*32 + ((lane >> 4) << 3) + j;
  float val;
  if (mode == 0)      val = src[k*128 + n];
  else if (mode == 1) val = (k < 127) ? W0[k*128 + n] : 0.f;
  else if (mode == 2) val = (k == 127) ? 0.f
                           : ((k < 127) ? W2[k*128 + n] : W2[(k-1)*128 + n]);
  else                val = (k < 155) ? Wd[k*64 + n] : 0.f;
  wt[idx] = (half_t)val;
}

// ---------------------------------------------------------------------------
// knn helpers
// ---------------------------------------------------------------------------
__device__ __forceinline__ void sort16_dual(int& va, int& vb, int l){
#pragma unroll
  for (int k = 2; k <= 16; k <<= 1){
#pragma unroll
    for (int j = k >> 1; j > 0; j >>= 1){
      int oa = dppx(va, j);
      int ob = dppx(vb, j);
      bool dirDesc = (l & k) != 0;
      bool lower   = (l & j) == 0;
      int mna = min(va, oa), mxa = max(va, oa);
      int mnb = min(vb, ob), mxb = max(vb, ob);
      va = (lower != dirDesc) ? mna : mxa;
      vb = (lower != dirDesc) ? mnb : mxb;
    }
  }
}

// 64-wide select-16-smallest (same network as previous rounds), dualized.
__device__ __forceinline__ void sel16_dual(int& xa, int& xb, int l){
  sort16_dual(xa, xb, l);
  xa = min(xa, __shfl_xor(xa, 31, 64));
  xb = min(xb, __shfl_xor(xb, 31, 64));
#pragma unroll
  for (int j = 8; j > 0; j >>= 1){
    int oa = dppx(xa, j), ob = dppx(xb, j);
    bool lower = (l & j) == 0;
    int mna = min(xa, oa), mxa = max(xa, oa);
    int mnb = min(xb, ob), mxb = max(xb, ob);
    xa = lower ? mna : mxa;
    xb = lower ? mnb : mxb;
  }
  xa = min(xa, __shfl_xor(xa, 63, 64));
  xb = min(xb, __shfl_xor(xb, 63, 64));
}

// Rare path: exact 16-round min-extraction by re-scanning lp with a 32-bit
// per-lane exclusion mask (register-light; keeps hot path at low VGPR).
__device__ __forceinline__ int knn_fallback(const float4* lp, float nqx,
                                            float nqy, float nqz, int lane){
  unsigned used = 0u;
  int keep = KINF;
#pragma unroll 1
  for (int rr = 0; rr < KNN_K; rr++){
    int best = KINF;
#pragma unroll 1
    for (int j = 0; j < 32; j++){
      int c = j*64 + lane;
      float4 P = lp[c];
      float s = fmaf(P.x, nqx, fmaf(P.y, nqy, fmaf(P.z, nqz, P.w)));
      int pv = (__float_as_int(s) & 0xFFFFF800) | c;
      pv = ((used >> j) & 1u) ? KINF : pv;
      best = min(best, pv);
    }
    int gm = best;
#pragma unroll
    for (int off2 = 1; off2 < 64; off2 <<= 1)
      gm = min(gm, __shfl_xor(gm, off2, 64));
    if (lane == rr) keep = gm;
    int gc = gm & 0x7FF;
    if ((gc & 63) == lane) used |= (1u << (gc >> 6));
  }
  return keep;
}

// Weighted-code gather + activation staging for one query (verbatim tail).
__device__ __forceinline__ void knn_tail(int keep, const float4* lp,
    float qx, float qy, float qz, const float* cc, const float* xyzdir,
    half_t* Ain, half_t* Din, int q, int lane){
  int ci = keep & 0x7FF;
  float4 P = lp[ci];
  float dx = qx - P.x, dy = qy - P.y, dz = qz - P.z;
  float d2 = fmaf(dz, dz, fmaf(dy, dy, dx*dx));
  float w = 1.0f / (d2 + 1e-16f);
  float wm = (lane < KNN_K) ? w : 0.0f;
  wm += dppxf(wm, 1);
  wm += dppxf(wm, 2);
  wm += __shfl_xor(wm, 4, 64);
  wm += dppxf(wm, 8);
  float wn = w / wm;

  float acc = 0.f;
#pragma unroll
  for (int i = 0; i < KNN_K; i++){
    int   cb = __shfl(ci, i, 64);
    float wb = __shfl(wn, i, 64);
    acc = fmaf(wb, cc[cb*CDIM + lane], acc);
  }
  size_t arow = (size_t)q * ASTRIDE;
  Ain[arow + lane] = (half_t)acc;

  float xv = (lane < 63) ? xyzdir[(size_t)q*90 + lane] : 0.f;
  Ain[arow + 64 + lane] = (half_t)xv;
  if (lane < 8) Ain[arow + 128 + lane] = (half_t)0.f;
  if (lane < 40){
    float dv = (lane < 27) ? xyzdir[(size_t)q*90 + 63 + lane] : 0.f;
    Din[(size_t)q*DSTRIDE + lane] = (half_t)dv;
  }
}

// ---------------------------------------------------------------------------
// Kernel 1 (R19 REWRITE): exact 16-NN, 2 queries per wave, 3 shared passes,
// NO per-lane candidate array. Pass1: packed per-lane minima for both
// queries (shared lp reads) -> dual bitonic -> tauA/tauB. Pass2: recompute
// packed values (identical fma order => identical bits) and compact both
// queries. Dual 64-wide selection. This halves lp LDS reads per query
// (32->16), drops VGPR to ~45 (no p[32]) -> __launch_bounds__(512,8),
// LDS 40KB/block -> 4 blocks/CU -> ~100% occupancy for a VALU-bound kernel.
// ---------------------------------------------------------------------------
__global__ __launch_bounds__(512, 8) void knn_kernel(const int* indices,
    const float* qpts, const float4* cpos4, const float* codes,
    const float* xyzdir, half_t* Ain, half_t* Din){
  __shared__ float4 lp[N_C];         // 32 KB
  __shared__ int    sl[16*SLCAP];    // 8 KB (2 slots per wave)
  int tid = threadIdx.x;
  int lane = tid & 63, wave = tid >> 6;
  int l = lane & 15;
  const float* cc = codes + (size_t)indices[0] * N_C * CDIM;

  for (int c = tid; c < N_C; c += 512) lp[c] = cpos4[c];
  __syncthreads();

  int qA = blockIdx.x * 16 + wave * 2;
  int qB = qA + 1;
  float qxA = qpts[qA*3 + 0], qyA = qpts[qA*3 + 1], qzA = qpts[qA*3 + 2];
  float qxB = qpts[qB*3 + 0], qyB = qpts[qB*3 + 1], qzB = qpts[qB*3 + 2];
  float nqxA = -2.0f*qxA, nqyA = -2.0f*qyA, nqzA = -2.0f*qzA;
  float nqxB = -2.0f*qxB, nqyB = -2.0f*qyB, nqzB = -2.0f*qzB;

  // Pass 1: packed per-lane minima (shared reads, both queries).
  int minA = KINF, minB = KINF;
#pragma unroll
  for (int j = 0; j < 32; j++){
    int c = j*64 + lane;
    float4 P = lp[c];
    float sA = fmaf(P.x, nqxA, fmaf(P.y, nqyA, fmaf(P.z, nqzA, P.w)));
    float sB = fmaf(P.x, nqxB, fmaf(P.y, nqyB, fmaf(P.z, nqzB, P.w)));
    minA = min(minA, (__float_as_int(sA) & 0xFFFFF800) | c);
    minB = min(minB, (__float_as_int(sB) & 0xFFFFF800) | c);
  }

  // tau = max of the four 16-group 4th-minima (guarantees >= 16 pass).
  int vA = minA, vB = minB;
  sort16_dual(vA, vB, l);
  int tauA = max(max(__shfl(vA, 3, 64), __shfl(vA, 19, 64)),
                 max(__shfl(vA, 35, 64), __shfl(vA, 51, 64)));
  int tauB = max(max(__shfl(vB, 3, 64), __shfl(vB, 19, 64)),
                 max(__shfl(vB, 35, 64), __shfl(vB, 51, 64)));

  // Pass 2: recompute + compact both queries (shared reads).
  int* slwA = &sl[(wave*2 + 0) * SLCAP];
  int* slwB = &sl[(wave*2 + 1) * SLCAP];
  int nA = 0, nB = 0;
#pragma unroll
  for (int j = 0; j < 32; j++){
    int c = j*64 + lane;
    float4 P = lp[c];
    float sA = fmaf(P.x, nqxA, fmaf(P.y, nqyA, fmaf(P.z, nqzA, P.w)));
    float sB = fmaf(P.x, nqxB, fmaf(P.y, nqyB, fmaf(P.z, nqzB, P.w)));
    int pvA = (__float_as_int(sA) & 0xFFFFF800) | c;
    int pvB = (__float_as_int(sB) & 0xFFFFF800) | c;

    bool cA = (pvA <= tauA);
    unsigned long long mA = __ballot(cA);
    int mbA = __builtin_amdgcn_mbcnt_hi((unsigned)(mA >> 32),
              __builtin_amdgcn_mbcnt_lo((unsigned)mA, 0));
    if (cA && nA <= 64) slwA[nA + mbA] = pvA;
    nA += (int)__popcll(mA);

    bool cB = (pvB <= tauB);
    unsigned long long mB = __ballot(cB);
    int mbB = __builtin_amdgcn_mbcnt_hi((unsigned)(mB >> 32),
              __builtin_amdgcn_mbcnt_lo((unsigned)mB, 0));
    if (cB && nB <= 64) slwB[nB + mbB] = pvB;
    nB += (int)__popcll(mB);
  }
  __builtin_amdgcn_wave_barrier();

  bool okA = (nA >= KNN_K && nA <= 64);
  bool okB = (nB >= KNN_K && nB <= 64);

  int xA = (lane < nA) ? slwA[lane] : KINF;
  int xB = (lane < nB) ? slwB[lane] : KINF;
  sel16_dual(xA, xB, l);
  int keepA = xA, keepB = xB;

  if (!okA) keepA = knn_fallback(lp, nqxA, nqyA, nqzA, lane);
  if (!okB) keepB = knn_fallback(lp, nqxB, nqyB, nqzB, lane);

  knn_tail(keepA, lp, qxA, qyA, qzA, cc, xyzdir, Ain, Din, qA, lane);
  knn_tail(keepB, lp, qxB, qyB, qzB, cc, xyzdir, Ain, Din, qB, lane);
}

// ---------------------------------------------------------------------------
// Kernel 2: fused MFMA MLP, 64 queries/block — EXACT R2 known-good version
// (the wave-private R3 rewrite regressed: 2x weight L2 traffic + serialized
// per-wave LDS round trips + lower occupancy. Reverted.)
// ---------------------------------------------------------------------------
template<int NCH, int NT>
__device__ inline void mfma_pl(const half_t* act, int astride, int rowbase,
                               const half_t* wlayer, int nt, int ktbase,
                               int tcolbase, v4f acc[2][NT], int lane){
  v8h breg[NCH*NT];
#pragma unroll
  for (int c = 0; c < NCH; c++){
#pragma unroll
    for (int t = 0; t < NT; t++){
      const half_t* bp = wlayer +
          ((size_t)(((ktbase + c)*nt + tcolbase + t) << 9) + (lane << 3));
      breg[c*NT + t] = *(const v8h*)bp;
    }
  }
  int m = lane & 15, quad = lane >> 4;
#pragma unroll
  for (int c = 0; c < NCH; c++){
    v8h a0 = *(const v8h*)&act[(rowbase + m)*astride + c*32 + quad*8];
    v8h a1 = *(const v8h*)&act[(rowbase + 16 + m)*astride + c*32 + quad*8];
#pragma unroll
    for (int t = 0; t < NT; t++){
      acc[0][t] = __builtin_amdgcn_mfma_f32_16x16x32_f16(a0, breg[c*NT + t], acc[0][t], 0, 0, 0);
      acc[1][t] = __builtin_amdgcn_mfma_f32_16x16x32_f16(a1, breg[c*NT + t], acc[1][t], 0, 0, 0);
    }
  }
}

template<int NT>
__device__ inline void epilogue64(v4f acc[2][NT], half_t* outb, int rowbase,
                                  int colbase, const float* bias, bool relu,
                                  int lane){
  int n = lane & 15, quad = lane >> 4;
#pragma unroll
  for (int t = 0; t < NT; t++){
    int col = colbase + t*16 + n;
    float bv = bias[col];
#pragma unroll
    for (int g = 0; g < 2; g++){
#pragma unroll
      for (int r = 0; r < 4; r++){
        float v = acc[g][t][r] + bv;
        if (relu) v = fmaxf(v, 0.f);
        outb[(rowbase + g*16 + quad*4 + r)*ASTRIDE + col] = (half_t)v;
      }
    }
  }
}

__global__ __launch_bounds__(512, 6) void mlp_mfma(
    const half_t* Ain, const half_t* Din, const half_t* wt,
    const float* b0, const float* b1, const float* b2, const float* b3,
    const float* bfb, const float* bdb,
    const float* Wsb, const float* bsb, const float* Wrb, const float* brb,
    float* out){
  __shared__ __align__(16) half_t Abuf[64*ASTRIDE];
  __shared__ __align__(16) half_t Pbuf[64*ASTRIDE];
  __shared__ __align__(16) half_t Qbuf[64*ASTRIDE];

  int tid = threadIdx.x, lane = tid & 63, wave = tid >> 6;
  int qbase = blockIdx.x * 64;

  for (int i = tid; i < 64*17; i += 512){
    int r = i / 17, c8 = i - r*17;
    *(uint4*)&Abuf[r*ASTRIDE + (c8 << 3)] =
        *(const uint4*)&Ain[(size_t)(qbase + r)*ASTRIDE + (c8 << 3)];
  }
  __syncthreads();

  int rowbase  = (wave >> 2) * 32;
  int colq     = wave & 3;
  int colbase  = colq * 32;
  int tcolbase = colq * 2;
  v4f acc[2][2];
  v4f accd[2][1];

  const half_t* wt0 = wt;
  const half_t* wt1 = wt + 16384;
  const half_t* wt2 = wt + 32768;
  const half_t* wt3 = wt + 65536;
  const half_t* wtf = wt + 81920;
  const half_t* wtd = wt + 98304;

#define ZACC22() { for (int g_ = 0; g_ < 2; g_++) for (int t_ = 0; t_ < 2; t_++) \
                   for (int e_ = 0; e_ < 4; e_++) acc[g_][t_][e_] = 0.f; }

  // L0: A @ W0 -> P (relu)
  ZACC22();
  mfma_pl<4,2>(Abuf, ASTRIDE, rowbase, wt0, 8, 0, tcolbase, acc, lane);
  epilogue64<2>(acc, Pbuf, rowbase, colbase, b0, true, lane);
  __syncthreads();

  // L1: P @ W1 -> Q (relu)
  ZACC22();
  mfma_pl<4,2>(Pbuf, ASTRIDE, rowbase, wt1, 8, 0, tcolbase, acc, lane);
  epilogue64<2>(acc, Qbuf, rowbase, colbase, b1, true, lane);
  __syncthreads();

  // L2: [input_xyz | h1] @ W2 -> P (relu)   (K = 256)
  ZACC22();
  mfma_pl<4,2>(Abuf, ASTRIDE, rowbase, wt2, 8, 0, tcolbase, acc, lane);
  mfma_pl<4,2>(Qbuf, ASTRIDE, rowbase, wt2, 8, 4, tcolbase, acc, lane);
  epilogue64<2>(acc, Pbuf, rowbase, colbase, b2, true, lane);
  __syncthreads();

  // L3: P @ W3 -> A (h3, kept for sigma; input_xyz dead)
  ZACC22();
  mfma_pl<4,2>(Pbuf, ASTRIDE, rowbase, wt3, 8, 0, tcolbase, acc, lane);
  epilogue64<2>(acc, Abuf, rowbase, colbase, b3, true, lane);
  __syncthreads();

  // Wf: A(h3) @ Wf -> P (no relu)
  ZACC22();
  mfma_pl<4,2>(Abuf, ASTRIDE, rowbase, wtf, 8, 0, tcolbase, acc, lane);
  epilogue64<2>(acc, Pbuf, rowbase, colbase, bfb, false, lane);
  __syncthreads();

  // Wd: [P(final) | Din(dir, straight from global/L2)] @ Wd -> Q[:,0:64]
#pragma unroll
  for (int g_ = 0; g_ < 2; g_++)
#pragma unroll
    for (int e_ = 0; e_ < 4; e_++) accd[g_][0][e_] = 0.f;
  mfma_pl<4,1>(Pbuf, ASTRIDE, rowbase, wtd, 4, 0, colq, accd, lane);
  mfma_pl<1,1>(Din + (size_t)qbase*DSTRIDE, DSTRIDE, rowbase, wtd, 4, 4, colq,
               accd, lane);
  epilogue64<1>(accd, Qbuf, rowbase, colq * 16, bdb, true, lane);
  __syncthreads();

  // Tail: sigma = h3(Abuf).Ws + bs ; rgb = d(Qbuf).Wr + br  (8 thr/query)
  {
    int q = tid >> 3, part = tid & 7;
    float s = 0.f;
#pragma unroll
    for (int k = 0; k < 16; k++){
      int kk = part*16 + k;
      s = fmaf((float)Abuf[q*ASTRIDE + kk], Wsb[kk], s);
    }
    s += __shfl_xor(s, 1, 64); s += __shfl_xor(s, 2, 64); s += __shfl_xor(s, 4, 64);

    float r3[3];
#pragma unroll
    for (int c2 = 0; c2 < 3; c2++){
      float rv = 0.f;
#pragma unroll
      for (int k = 0; k < 8; k++){
        int kk = part*8 + k;
        rv = fmaf((float)Qbuf[q*ASTRIDE + kk], Wrb[kk*3 + c2], rv);
      }
      rv += __shfl_xor(rv, 1, 64); rv += __shfl_xor(rv, 2, 64); rv += __shfl_xor(rv, 4, 64);
      r3[c2] = rv;
    }
    if (part == 0){
      size_t ob = ((size_t)(qbase + q)) * 4;
      out[ob + 0] = r3[0] + brb[0];
      out[ob + 1] = r3[1] + brb[1];
      out[ob + 2] = r3[2] + brb[2];
      out[ob + 3] = s + bsb[0];
    }
  }
}

// ---------------------------------------------------------------------------
extern "C" void kernel_launch(void* const* d_in, const int* in_sizes, int n_in,
                              void* d_out, int out_size, void* d_ws, size_t ws_size,
                              hipStream_t stream){
  (void)in_sizes; (void)n_in; (void)out_size; (void)ws_size;

  const int*   indices = (const int*)d_in[0];
  const float* qpts    = (const float*)d_in[1];
  const float* xyzdir  = (const float*)d_in[2];
  const float* cpos    = (const float*)d_in[3];
  const float* codes   = (const float*)d_in[4];
  const float* W0 = (const float*)d_in[5];
  const float* b0 = (const float*)d_in[6];
  const float* W1 = (const float*)d_in[7];
  const float* b1 = (const float*)d_in[8];
  const float* W2 = (const float*)d_in[9];
  const float* b2 = (const float*)d_in[10];
  const float* W3 = (const float*)d_in[11];
  const float* b3 = (const float*)d_in[12];
  const float* Wf = (const float*)d_in[13];
  const float* bf = (const float*)d_in[14];
  const float* Wd = (const float*)d_in[15];
  const float* bd = (const float*)d_in[16];
  const float* Ws = (const float*)d_in[17];
  const float* bs = (const float*)d_in[18];
  const float* Wr = (const float*)d_in[19];
  const float* br = (const float*)d_in[20];

  // ws layout (16-B aligned): Ain | Din | wt | cpos4
  half_t* Ain   = (half_t*)d_ws;                                   // 17,825,792 B
  half_t* Din   = (half_t*)((char*)d_ws + 17825792);               //  5,242,880 B
  half_t* wt    = (half_t*)((char*)d_ws + 17825792 + 5242880);     //    217,088 B
  float4* cpos4 = (float4*)((char*)d_ws + 17825792 + 5242880 + 217088);

  wtrans_kernel<<<(110592 + 255)/256, 256, 0, stream>>>(W0, W1, W2, W3, Wf, Wd,
                                                        indices, cpos, wt, cpos4);
  knn_kernel<<<N_Q/16, 512, 0, stream>>>(indices, qpts, cpos4, codes, xyzdir,
                                         Ain, Din);
  mlp_mfma<<<N_Q/64, 512, 0, stream>>>(Ain, Din, wt,
                                       b0, b1, b2, b3, bf, bd, Ws, bs, Wr, br,
                                       (float*)d_out);
}

// Round 5
// 209.416 us; speedup vs baseline: 1.1439x; 1.1165x over previous
//
#include <hip/hip_runtime.h>

#define N_Q   65536
#define N_C   2048
#define KNN_K 16
#define CDIM  64
#define SLCAP 128
#define KINF  0x7FFFFFFF
#define WSZ   108544  // halves per weight image

typedef _Float16 half_t;
typedef float v4f __attribute__((ext_vector_type(4)));
typedef half_t v8h __attribute__((ext_vector_type(8)));

#define ASTRIDE 136   // 128 + 8 pad (halves); row = 272 B = 17*16 B
#define DSTRIDE 40    // 32 + 8 pad

// ---------------------------------------------------------------------------
// DPP lane-xor for the serially dependent bitonic chains.
// ---------------------------------------------------------------------------
__device__ __forceinline__ int dppx(int v, int j){
  if (j == 1) return __builtin_amdgcn_mov_dpp(v, 0xB1,  0xF, 0xF, true); // quad_perm [1,0,3,2]
  if (j == 2) return __builtin_amdgcn_mov_dpp(v, 0x4E,  0xF, 0xF, true); // quad_perm [2,3,0,1]
  if (j == 8) return __builtin_amdgcn_mov_dpp(v, 0x128, 0xF, 0xF, true); // row_ror:8
  return __shfl_xor(v, j, 64);
}
__device__ __forceinline__ float dppxf(float v, int j){
  return __int_as_float(dppx(__float_as_int(v), j));
}

// ---------------------------------------------------------------------------
// Kernel 0: weights -> fp16 MFMA-fragment-order tiles + cpos4 (unchanged)
// ---------------------------------------------------------------------------
__global__ void wtrans_kernel(const float* W0, const float* W1, const float* W2,
                              const float* W3, const float* Wf, const float* Wd,
                              const int* indices, const float* cpos,
                              half_t* wt, float4* cpos4){
  int idx = blockIdx.x * 256 + threadIdx.x;
  if (idx >= 110592) return;
  if (idx >= WSZ){
    int i = idx - WSZ;
    const float* cp = cpos + (size_t)indices[0] * N_C * 3;
    float x = cp[i*3 + 0], y = cp[i*3 + 1], z = cp[i*3 + 2];
    cpos4[i] = make_float4(x, y, z, fmaf(x, x, fmaf(y, y, fmaf(z, z, 4.0f))));
    return;
  }
  int base, nt, mode;            // mode: 0 plain(src), 1 W0, 2 W2, 3 Wd
  const float* src = W1;
  if (idx < 16384){ base = 0; nt = 8; mode = 1; }
  else if (idx < 32768){ base = 16384; nt = 8; mode = 0; src = W1; }
  else if (idx < 65536){ base = 32768; nt = 8; mode = 2; }
  else if (idx < 81920){ base = 65536; nt = 8; mode = 0; src = W3; }
  else if (idx < 98304){ base = 81920; nt = 8; mode = 0; src = Wf; }
  else { base = 98304; nt = 4; mode = 3; }
  int i = idx - base;
  int tile = i >> 9, e = i & 511;
  int lane = e >> 3, j = e & 7;
  int k0idx = tile / nt, tcol = tile - k0idx*nt;
  int n = tcol*16 + (lane & 15);
  int k = k0idx*32 + ((lane >> 4) << 3) + j;
  float val;
  if (mode == 0)      val = src[k*128 + n];
  else if (mode == 1) val = (k < 127) ? W0[k*128 + n] : 0.f;
  else if (mode == 2) val = (k == 127) ? 0.f
                           : ((k < 127) ? W2[k*128 + n] : W2[(k-1)*128 + n]);
  else                val = (k < 155) ? Wd[k*64 + n] : 0.f;
  wt[idx] = (half_t)val;
}

// ---------------------------------------------------------------------------
// Kernel 1: exact 16-NN + activation staging — R2 code verbatim, ONE change:
// __launch_bounds__(512, 8). LDS 36,864 B -> 4 blocks/CU fit (147 KB);
// the (512,6) declaration was the only occupancy cap (70% -> ~100%).
// Falsifier: if FETCH_SIZE jumps (spill traffic), revert to (512,6).
// ---------------------------------------------------------------------------
__global__ __launch_bounds__(512, 8) void knn_kernel(const int* indices,
    const float* qpts, const float4* cpos4, const float* codes,
    const float* xyzdir, half_t* Ain, half_t* Din){
  __shared__ float4 lp[N_C];        // 32 KB
  __shared__ int    sl[8*SLCAP];    // 4 KB
  int tid = threadIdx.x;
  int lane = tid & 63, wave = tid >> 6;
  int l = lane & 15;                // lane within 16-group
  const float* cc = codes + (size_t)indices[0] * N_C * CDIM;

  for (int c = tid; c < N_C; c += 512) lp[c] = cpos4[c];
  __syncthreads();

  int q = blockIdx.x * 8 + wave;
  float qx = qpts[q*3 + 0];
  float qy = qpts[q*3 + 1];
  float qz = qpts[q*3 + 2];
  float nqx = -2.0f*qx, nqy = -2.0f*qy, nqz = -2.0f*qz;

  int p[32];
#pragma unroll
  for (int j = 0; j < 32; j++){
    int c = j*64 + lane;
    float4 P = lp[c];
    float s = fmaf(P.x, nqx, fmaf(P.y, nqy, fmaf(P.z, nqz, P.w)));  // > 0
    int pv = (__float_as_int(s) & 0xFFFFF800) | c;
    asm("" : "+v"(pv));   // opaque def: cannot be rematerialized from LDS
    p[j] = pv;
  }

  int lm = p[0];
#pragma unroll
  for (int j = 1; j < 32; j++) lm = min(lm, p[j]);

  int v = lm;
#pragma unroll
  for (int k = 2; k <= 16; k <<= 1){
#pragma unroll
    for (int j = k >> 1; j > 0; j >>= 1){
      int o = dppx(v, j);
      bool dirDesc = (l & k) != 0;
      bool lower   = (l & j) == 0;
      int mn = min(v, o), mx = max(v, o);
      v = (lower != dirDesc) ? mn : mx;
    }
  }
  int t0 = __shfl(v, 3, 64),  t1 = __shfl(v, 19, 64);
  int t2 = __shfl(v, 35, 64), t3 = __shfl(v, 51, 64);
  int tau = max(max(t0, t1), max(t2, t3));

  int* slw = &sl[wave * SLCAP];
  int n = 0;
#pragma unroll
  for (int j = 0; j < 32; j++){
    bool c = (p[j] <= tau);
    unsigned long long m = __ballot(c);
    if (m){
      if (n <= 64){
        if (c){
          int mb = __builtin_amdgcn_mbcnt_hi((unsigned)(m >> 32),
                   __builtin_amdgcn_mbcnt_lo((unsigned)m, 0));
          slw[n + mb] = p[j];
        }
      }
      n += (int)__popcll(m);
    }
  }
  __builtin_amdgcn_wave_barrier();

  int keep;
  if (n >= KNN_K && n <= 64){
    int x = (lane < n) ? slw[lane] : KINF;
#pragma unroll
    for (int k = 2; k <= 16; k <<= 1){
#pragma unroll
      for (int j = k >> 1; j > 0; j >>= 1){
        int o = dppx(x, j);
        bool dirDesc = (l & k) != 0;
        bool lower   = (l & j) == 0;
        int mn = min(x, o), mx = max(x, o);
        x = (lower != dirDesc) ? mn : mx;
      }
    }
    x = min(x, __shfl_xor(x, 31, 64));
#pragma unroll
    for (int j = 8; j > 0; j >>= 1){
      int o = dppx(x, j);
      bool lower = (l & j) == 0;
      int mn = min(x, o), mx = max(x, o);
      x = lower ? mn : mx;
    }
    x = min(x, __shfl_xor(x, 63, 64));
    keep = x;
  } else {
    keep = KINF;
#pragma unroll 1
    for (int rr = 0; rr < KNN_K; rr++){
      int lmf = p[0];
#pragma unroll
      for (int j = 1; j < 32; j++) lmf = min(lmf, p[j]);
      int gm = lmf;
#pragma unroll
      for (int off2 = 1; off2 < 64; off2 <<= 1)
        gm = min(gm, __shfl_xor(gm, off2, 64));
      if (lane == rr) keep = gm;
#pragma unroll
      for (int j = 0; j < 32; j++) p[j] = (p[j] == gm) ? KINF : p[j];
    }
  }

  int ci = keep & 0x7FF;
  float4 P = lp[ci];
  float dx = qx - P.x, dy = qy - P.y, dz = qz - P.z;
  float d2 = fmaf(dz, dz, fmaf(dy, dy, dx*dx));
  float w = 1.0f / (d2 + 1e-16f);
  float wm = (lane < KNN_K) ? w : 0.0f;
  wm += dppxf(wm, 1);
  wm += dppxf(wm, 2);
  wm += __shfl_xor(wm, 4, 64);
  wm += dppxf(wm, 8);
  float wn = w / wm;

  float acc = 0.f;
#pragma unroll
  for (int i = 0; i < KNN_K; i++){
    int   cb = __shfl(ci, i, 64);
    float wb = __shfl(wn, i, 64);
    acc = fmaf(wb, cc[cb*CDIM + lane], acc);
  }
  size_t arow = (size_t)q * ASTRIDE;
  Ain[arow + lane] = (half_t)acc;

  float xv = (lane < 63) ? xyzdir[(size_t)q*90 + lane] : 0.f;
  Ain[arow + 64 + lane] = (half_t)xv;
  if (lane < 8) Ain[arow + 128 + lane] = (half_t)0.f;
  if (lane < 40){
    float dv = (lane < 27) ? xyzdir[(size_t)q*90 + 63 + lane] : 0.f;
    Din[(size_t)q*DSTRIDE + lane] = (half_t)dv;
  }
}

// ---------------------------------------------------------------------------
// Kernel 2: fused MFMA MLP, 64 queries/block — R2 known-good version, frozen.
// ---------------------------------------------------------------------------
template<int NCH, int NT>
__device__ inline void mfma_pl(const half_t* act, int astride, int rowbase,
                               const half_t* wlayer, int nt, int ktbase,
                               int tcolbase, v4f acc[2][NT], int lane){
  v8h breg[NCH*NT];
#pragma unroll
  for (int c = 0; c < NCH; c++){
#pragma unroll
    for (int t = 0; t < NT; t++){
      const half_t* bp = wlayer +
          ((size_t)(((ktbase + c)*nt + tcolbase + t) << 9) + (lane << 3));
      breg[c*NT + t] = *(const v8h*)bp;
    }
  }
  int m = lane & 15, quad = lane >> 4;
#pragma unroll
  for (int c = 0; c < NCH; c++){
    v8h a0 = *(const v8h*)&act[(rowbase + m)*astride + c*32 + quad*8];
    v8h a1 = *(const v8h*)&act[(rowbase + 16 + m)*astride + c*32 + quad*8];
#pragma unroll
    for (int t = 0; t < NT; t++){
      acc[0][t] = __builtin_amdgcn_mfma_f32_16x16x32_f16(a0, breg[c*NT + t], acc[0][t], 0, 0, 0);
      acc[1][t] = __builtin_amdgcn_mfma_f32_16x16x32_f16(a1, breg[c*NT + t], acc[1][t], 0, 0, 0);
    }
  }
}

template<int NT>
__device__ inline void epilogue64(v4f acc[2][NT], half_t* outb, int rowbase,
                                  int colbase, const float* bias, bool relu,
                                  int lane){
  int n = lane & 15, quad = lane >> 4;
#pragma unroll
  for (int t = 0; t < NT; t++){
    int col = colbase + t*16 + n;
    float bv = bias[col];
#pragma unroll
    for (int g = 0; g < 2; g++){
#pragma unroll
      for (int r = 0; r < 4; r++){
        float v = acc[g][t][r] + bv;
        if (relu) v = fmaxf(v, 0.f);
        outb[(rowbase + g*16 + quad*4 + r)*ASTRIDE + col] = (half_t)v;
      }
    }
  }
}

__global__ __launch_bounds__(512, 6) void mlp_mfma(
    const half_t* Ain, const half_t* Din, const half_t* wt,
    const float* b0, const float* b1, const float* b2, const float* b3,
    const float* bfb, const float* bdb,
    const float* Wsb, const float* bsb, const float* Wrb, const float* brb,
    float* out){
  __shared__ __align__(16) half_t Abuf[64*ASTRIDE];
  __shared__ __align__(16) half_t Pbuf[64*ASTRIDE];
  __shared__ __align__(16) half_t Qbuf[64*ASTRIDE];

  int tid = threadIdx.x, lane = tid & 63, wave = tid >> 6;
  int qbase = blockIdx.x * 64;

  for (int i = tid; i < 64*17; i += 512){
    int r = i / 17, c8 = i - r*17;
    *(uint4*)&Abuf[r*ASTRIDE + (c8 << 3)] =
        *(const uint4*)&Ain[(size_t)(qbase + r)*ASTRIDE + (c8 << 3)];
  }
  __syncthreads();

  int rowbase  = (wave >> 2) * 32;
  int colq     = wave & 3;
  int colbase  = colq * 32;
  int tcolbase = colq * 2;
  v4f acc[2][2];
  v4f accd[2][1];

  const half_t* wt0 = wt;
  const half_t* wt1 = wt + 16384;
  const half_t* wt2 = wt + 32768;
  const half_t* wt3 = wt + 65536;
  const half_t* wtf = wt + 81920;
  const half_t* wtd = wt + 98304;

#define ZACC22() { for (int g_ = 0; g_ < 2; g_++) for (int t_ = 0; t_ < 2; t_++) \
                   for (int e_ = 0; e_ < 4; e_++) acc[g_][t_][e_] = 0.f; }

  // L0: A @ W0 -> P (relu)
  ZACC22();
  mfma_pl<4,2>(Abuf, ASTRIDE, rowbase, wt0, 8, 0, tcolbase, acc, lane);
  epilogue64<2>(acc, Pbuf, rowbase, colbase, b0, true, lane);
  __syncthreads();

  // L1: P @ W1 -> Q (relu)
  ZACC22();
  mfma_pl<4,2>(Pbuf, ASTRIDE, rowbase, wt1, 8, 0, tcolbase, acc, lane);
  epilogue64<2>(acc, Qbuf, rowbase, colbase, b1, true, lane);
  __syncthreads();

  // L2: [input_xyz | h1] @ W2 -> P (relu)   (K = 256)
  ZACC22();
  mfma_pl<4,2>(Abuf, ASTRIDE, rowbase, wt2, 8, 0, tcolbase, acc, lane);
  mfma_pl<4,2>(Qbuf, ASTRIDE, rowbase, wt2, 8, 4, tcolbase, acc, lane);
  epilogue64<2>(acc, Pbuf, rowbase, colbase, b2, true, lane);
  __syncthreads();

  // L3: P @ W3 -> A (h3, kept for sigma; input_xyz dead)
  ZACC22();
  mfma_pl<4,2>(Pbuf, ASTRIDE, rowbase, wt3, 8, 0, tcolbase, acc, lane);
  epilogue64<2>(acc, Abuf, rowbase, colbase, b3, true, lane);
  __syncthreads();

  // Wf: A(h3) @ Wf -> P (no relu)
  ZACC22();
  mfma_pl<4,2>(Abuf, ASTRIDE, rowbase, wtf, 8, 0, tcolbase, acc, lane);
  epilogue64<2>(acc, Pbuf, rowbase, colbase, bfb, false, lane);
  __syncthreads();

  // Wd: [P(final) | Din(dir, straight from global/L2)] @ Wd -> Q[:,0:64]
#pragma unroll
  for (int g_ = 0; g_ < 2; g_++)
#pragma unroll
    for (int e_ = 0; e_ < 4; e_++) accd[g_][0][e_] = 0.f;
  mfma_pl<4,1>(Pbuf, ASTRIDE, rowbase, wtd, 4, 0, colq, accd, lane);
  mfma_pl<1,1>(Din + (size_t)qbase*DSTRIDE, DSTRIDE, rowbase, wtd, 4, 4, colq,
               accd, lane);
  epilogue64<1>(accd, Qbuf, rowbase, colq * 16, bdb, true, lane);
  __syncthreads();

  // Tail: sigma = h3(Abuf).Ws + bs ; rgb = d(Qbuf).Wr + br  (8 thr/query)
  {
    int q = tid >> 3, part = tid & 7;
    float s = 0.f;
#pragma unroll
    for (int k = 0; k < 16; k++){
      int kk = part*16 + k;
      s = fmaf((float)Abuf[q*ASTRIDE + kk], Wsb[kk], s);
    }
    s += __shfl_xor(s, 1, 64); s += __shfl_xor(s, 2, 64); s += __shfl_xor(s, 4, 64);

    float r3[3];
#pragma unroll
    for (int c2 = 0; c2 < 3; c2++){
      float rv = 0.f;
#pragma unroll
      for (int k = 0; k < 8; k++){
        int kk = part*8 + k;
        rv = fmaf((float)Qbuf[q*ASTRIDE + kk], Wrb[kk*3 + c2], rv);
      }
      rv += __shfl_xor(rv, 1, 64); rv += __shfl_xor(rv, 2, 64); rv += __shfl_xor(rv, 4, 64);
      r3[c2] = rv;
    }
    if (part == 0){
      size_t ob = ((size_t)(qbase + q)) * 4;
      out[ob + 0] = r3[0] + brb[0];
      out[ob + 1] = r3[1] + brb[1];
      out[ob + 2] = r3[2] + brb[2];
      out[ob + 3] = s + bsb[0];
    }
  }
}

// ---------------------------------------------------------------------------
extern "C" void kernel_launch(void* const* d_in, const int* in_sizes, int n_in,
                              void* d_out, int out_size, void* d_ws, size_t ws_size,
                              hipStream_t stream){
  (void)in_sizes; (void)n_in; (void)out_size; (void)ws_size;

  const int*   indices = (const int*)d_in[0];
  const float* qpts    = (const float*)d_in[1];
  const float* xyzdir  = (const float*)d_in[2];
  const float* cpos    = (const float*)d_in[3];
  const float* codes   = (const float*)d_in[4];
  const float* W0 = (const float*)d_in[5];
  const float* b0 = (const float*)d_in[6];
  const float* W1 = (const float*)d_in[7];
  const float* b1 = (const float*)d_in[8];
  const float* W2 = (const float*)d_in[9];
  const float* b2 = (const float*)d_in[10];
  const float* W3 = (const float*)d_in[11];
  const float* b3 = (const float*)d_in[12];
  const float* Wf = (const float*)d_in[13];
  const float* bf = (const float*)d_in[14];
  const float* Wd = (const float*)d_in[15];
  const float* bd = (const float*)d_in[16];
  const float* Ws = (const float*)d_in[17];
  const float* bs = (const float*)d_in[18];
  const float* Wr = (const float*)d_in[19];
  const float* br = (const float*)d_in[20];

  // ws layout (16-B aligned): Ain | Din | wt | cpos4
  half_t* Ain   = (half_t*)d_ws;                                   // 17,825,792 B
  half_t* Din   = (half_t*)((char*)d_ws + 17825792);               //  5,242,880 B
  half_t* wt    = (half_t*)((char*)d_ws + 17825792 + 5242880);     //    217,088 B
  float4* cpos4 = (float4*)((char*)d_ws + 17825792 + 5242880 + 217088);

  wtrans_kernel<<<(110592 + 255)/256, 256, 0, stream>>>(W0, W1, W2, W3, Wf, Wd,
                                                        indices, cpos, wt, cpos4);
  knn_kernel<<<N_Q/8, 512, 0, stream>>>(indices, qpts, cpos4, codes, xyzdir,
                                        Ain, Din);
  mlp_mfma<<<N_Q/64, 512, 0, stream>>>(Ain, Din, wt,
                                       b0, b1, b2, b3, bf, bd, Ws, bs, Wr, br,
                                       (float*)d_out);
}

// Round 6
// 203.214 us; speedup vs baseline: 1.1788x; 1.0305x over previous
//
#include <hip/hip_runtime.h>

#define N_Q   65536
#define N_C   2048
#define KNN_K 16
#define CDIM  64
#define SLCAP 128
#define KINF  0x7FFFFFFF
#define WSZ   108544  // halves per weight image

typedef _Float16 half_t;
typedef float v4f __attribute__((ext_vector_type(4)));
typedef half_t v8h __attribute__((ext_vector_type(8)));

#define ASTRIDE 136   // 128 + 8 pad (halves); row = 272 B = 17*16 B
#define DSTRIDE 40    // 32 + 8 pad

// ---------------------------------------------------------------------------
// DPP lane-xor (kept for the wm tree reduction).
// ---------------------------------------------------------------------------
__device__ __forceinline__ int dppx(int v, int j){
  if (j == 1) return __builtin_amdgcn_mov_dpp(v, 0xB1,  0xF, 0xF, true); // quad_perm [1,0,3,2]
  if (j == 2) return __builtin_amdgcn_mov_dpp(v, 0x4E,  0xF, 0xF, true); // quad_perm [2,3,0,1]
  if (j == 8) return __builtin_amdgcn_mov_dpp(v, 0x128, 0xF, 0xF, true); // row_ror:8
  return __shfl_xor(v, j, 64);
}
__device__ __forceinline__ float dppxf(float v, int j){
  return __int_as_float(dppx(__float_as_int(v), j));
}

// Exact 16th-smallest of 64 per-lane ints (values > 0, unique except KINF
// padding) via bitwise binary search. ~31 rounds x {1 VALU cmp + SALU} —
// replaces a full bitonic sort in an issue-bound kernel. Returns P such
// that count(x < P) < 16 and count(x <= P) >= 16 (P = 16th smallest).
__device__ __forceinline__ int select16th(int x){
  int P = 0;
#pragma unroll
  for (int b = 30; b >= 0; --b){
    int cand = P | (1 << b);
    unsigned long long m = __ballot(x < cand);
    if ((int)__popcll(m) < 16) P = cand;
  }
  return P;
}

// ---------------------------------------------------------------------------
// Kernel 0: weights -> fp16 MFMA-fragment-order tiles + cpos4 (unchanged)
// ---------------------------------------------------------------------------
__global__ void wtrans_kernel(const float* W0, const float* W1, const float* W2,
                              const float* W3, const float* Wf, const float* Wd,
                              const int* indices, const float* cpos,
                              half_t* wt, float4* cpos4){
  int idx = blockIdx.x * 256 + threadIdx.x;
  if (idx >= 110592) return;
  if (idx >= WSZ){
    int i = idx - WSZ;
    const float* cp = cpos + (size_t)indices[0] * N_C * 3;
    float x = cp[i*3 + 0], y = cp[i*3 + 1], z = cp[i*3 + 2];
    cpos4[i] = make_float4(x, y, z, fmaf(x, x, fmaf(y, y, fmaf(z, z, 4.0f))));
    return;
  }
  int base, nt, mode;            // mode: 0 plain(src), 1 W0, 2 W2, 3 Wd
  const float* src = W1;
  if (idx < 16384){ base = 0; nt = 8; mode = 1; }
  else if (idx < 32768){ base = 16384; nt = 8; mode = 0; src = W1; }
  else if (idx < 65536){ base = 32768; nt = 8; mode = 2; }
  else if (idx < 81920){ base = 65536; nt = 8; mode = 0; src = W3; }
  else if (idx < 98304){ base = 81920; nt = 8; mode = 0; src = Wf; }
  else { base = 98304; nt = 4; mode = 3; }
  int i = idx - base;
  int tile = i >> 9, e = i & 511;
  int lane = e >> 3, j = e & 7;
  int k0idx = tile / nt, tcol = tile - k0idx*nt;
  int n = tcol*16 + (lane & 15);
  int k = k0idx*32 + ((lane >> 4) << 3) + j;
  float val;
  if (mode == 0)      val = src[k*128 + n];
  else if (mode == 1) val = (k < 127) ? W0[k*128 + n] : 0.f;
  else if (mode == 2) val = (k == 127) ? 0.f
                           : ((k < 127) ? W2[k*128 + n] : W2[(k-1)*128 + n]);
  else                val = (k < 155) ? Wd[k*64 + n] : 0.f;
  wt[idx] = (half_t)val;
}

// ---------------------------------------------------------------------------
// Kernel 1: exact 16-NN + activation staging. R21 change: both bitonic
// sorts replaced by exact-16th bitwise binary search (select16th).
// Sorted ORDER of the 16 winners is not needed (wm is a tree reduction;
// acc sum order only perturbs ~1e-9); only the SET matters, and the set
// from select16th is bit-identical to the sort version (unique packed
// values). Saves ~190 VALU-issues/query in an issue-bound kernel.
// Distance pass, compaction, fallback, tail: R2 verbatim.
// ---------------------------------------------------------------------------
__global__ __launch_bounds__(512, 6) void knn_kernel(const int* indices,
    const float* qpts, const float4* cpos4, const float* codes,
    const float* xyzdir, half_t* Ain, half_t* Din){
  __shared__ float4 lp[N_C];        // 32 KB
  __shared__ int    sl[8*SLCAP];    // 4 KB
  int tid = threadIdx.x;
  int lane = tid & 63, wave = tid >> 6;
  const float* cc = codes + (size_t)indices[0] * N_C * CDIM;

  for (int c = tid; c < N_C; c += 512) lp[c] = cpos4[c];
  __syncthreads();

  int q = blockIdx.x * 8 + wave;
  float qx = qpts[q*3 + 0];
  float qy = qpts[q*3 + 1];
  float qz = qpts[q*3 + 2];
  float nqx = -2.0f*qx, nqy = -2.0f*qy, nqz = -2.0f*qz;

  int p[32];
#pragma unroll
  for (int j = 0; j < 32; j++){
    int c = j*64 + lane;
    float4 P = lp[c];
    float s = fmaf(P.x, nqx, fmaf(P.y, nqy, fmaf(P.z, nqz, P.w)));  // > 0
    int pv = (__float_as_int(s) & 0xFFFFF800) | c;
    asm("" : "+v"(pv));   // opaque def: cannot be rematerialized from LDS
    p[j] = pv;
  }

  int lm = p[0];
#pragma unroll
  for (int j = 1; j < 32; j++) lm = min(lm, p[j]);

  // tau = EXACT 16th smallest lane-min (>=16 candidates <= tau guaranteed:
  // the 16 lanes with min <= tau each contribute their min).
  int tau = select16th(lm);

  int* slw = &sl[wave * SLCAP];
  int n = 0;
#pragma unroll
  for (int j = 0; j < 32; j++){
    bool c = (p[j] <= tau);
    unsigned long long m = __ballot(c);
    if (m){
      if (n <= 64){
        if (c){
          int mb = __builtin_amdgcn_mbcnt_hi((unsigned)(m >> 32),
                   __builtin_amdgcn_mbcnt_lo((unsigned)m, 0));
          slw[n + mb] = p[j];
        }
      }
      n += (int)__popcll(m);
    }
  }
  __builtin_amdgcn_wave_barrier();

  int keep;
  if (n >= KNN_K && n <= 64){
    int x = (lane < n) ? slw[lane] : KINF;
    // exact 16th smallest of the n candidates; winners = x <= P2
    // (exactly 16 lanes: values unique, P2 < KINF since n >= 16).
    int P2 = select16th(x);
    unsigned long long wmask = __ballot(x <= P2);
    int pos = __builtin_amdgcn_mbcnt_hi((unsigned)(wmask >> 32),
              __builtin_amdgcn_mbcnt_lo((unsigned)wmask, 0));
    if (x <= P2) slw[pos] = x;          // compact winners to slots 0..15
    __builtin_amdgcn_wave_barrier();
    keep = (lane < KNN_K) ? slw[lane] : KINF;
  } else {
    keep = KINF;
#pragma unroll 1
    for (int rr = 0; rr < KNN_K; rr++){
      int lmf = p[0];
#pragma unroll
      for (int j = 1; j < 32; j++) lmf = min(lmf, p[j]);
      int gm = lmf;
#pragma unroll
      for (int off2 = 1; off2 < 64; off2 <<= 1)
        gm = min(gm, __shfl_xor(gm, off2, 64));
      if (lane == rr) keep = gm;
#pragma unroll
      for (int j = 0; j < 32; j++) p[j] = (p[j] == gm) ? KINF : p[j];
    }
  }

  int ci = keep & 0x7FF;
  float4 P = lp[ci];
  float dx = qx - P.x, dy = qy - P.y, dz = qz - P.z;
  float d2 = fmaf(dz, dz, fmaf(dy, dy, dx*dx));
  float w = 1.0f / (d2 + 1e-16f);
  float wm = (lane < KNN_K) ? w : 0.0f;
  // consumers (__shfl of wn) sit in lanes 0-15 -> within-16 sum suffices
  wm += dppxf(wm, 1);
  wm += dppxf(wm, 2);
  wm += __shfl_xor(wm, 4, 64);
  wm += dppxf(wm, 8);
  float wn = w / wm;

  float acc = 0.f;
#pragma unroll
  for (int i = 0; i < KNN_K; i++){
    int   cb = __shfl(ci, i, 64);
    float wb = __shfl(wn, i, 64);
    acc = fmaf(wb, cc[cb*CDIM + lane], acc);
  }
  size_t arow = (size_t)q * ASTRIDE;
  Ain[arow + lane] = (half_t)acc;

  float xv = (lane < 63) ? xyzdir[(size_t)q*90 + lane] : 0.f;
  Ain[arow + 64 + lane] = (half_t)xv;
  if (lane < 8) Ain[arow + 128 + lane] = (half_t)0.f;
  if (lane < 40){
    float dv = (lane < 27) ? xyzdir[(size_t)q*90 + 63 + lane] : 0.f;
    Din[(size_t)q*DSTRIDE + lane] = (half_t)dv;
  }
}

// ---------------------------------------------------------------------------
// Kernel 2: fused MFMA MLP, 64 queries/block — R2 known-good version, frozen.
// ---------------------------------------------------------------------------
template<int NCH, int NT>
__device__ inline void mfma_pl(const half_t* act, int astride, int rowbase,
                               const half_t* wlayer, int nt, int ktbase,
                               int tcolbase, v4f acc[2][NT], int lane){
  v8h breg[NCH*NT];
#pragma unroll
  for (int c = 0; c < NCH; c++){
#pragma unroll
    for (int t = 0; t < NT; t++){
      const half_t* bp = wlayer +
          ((size_t)(((ktbase + c)*nt + tcolbase + t) << 9) + (lane << 3));
      breg[c*NT + t] = *(const v8h*)bp;
    }
  }
  int m = lane & 15, quad = lane >> 4;
#pragma unroll
  for (int c = 0; c < NCH; c++){
    v8h a0 = *(const v8h*)&act[(rowbase + m)*astride + c*32 + quad*8];
    v8h a1 = *(const v8h*)&act[(rowbase + 16 + m)*astride + c*32 + quad*8];
#pragma unroll
    for (int t = 0; t < NT; t++){
      acc[0][t] = __builtin_amdgcn_mfma_f32_16x16x32_f16(a0, breg[c*NT + t], acc[0][t], 0, 0, 0);
      acc[1][t] = __builtin_amdgcn_mfma_f32_16x16x32_f16(a1, breg[c*NT + t], acc[1][t], 0, 0, 0);
    }
  }
}

template<int NT>
__device__ inline void epilogue64(v4f acc[2][NT], half_t* outb, int rowbase,
                                  int colbase, const float* bias, bool relu,
                                  int lane){
  int n = lane & 15, quad = lane >> 4;
#pragma unroll
  for (int t = 0; t < NT; t++){
    int col = colbase + t*16 + n;
    float bv = bias[col];
#pragma unroll
    for (int g = 0; g < 2; g++){
#pragma unroll
      for (int r = 0; r < 4; r++){
        float v = acc[g][t][r] + bv;
        if (relu) v = fmaxf(v, 0.f);
        outb[(rowbase + g*16 + quad*4 + r)*ASTRIDE + col] = (half_t)v;
      }
    }
  }
}

__global__ __launch_bounds__(512, 6) void mlp_mfma(
    const half_t* Ain, const half_t* Din, const half_t* wt,
    const float* b0, const float* b1, const float* b2, const float* b3,
    const float* bfb, const float* bdb,
    const float* Wsb, const float* bsb, const float* Wrb, const float* brb,
    float* out){
  __shared__ __align__(16) half_t Abuf[64*ASTRIDE];
  __shared__ __align__(16) half_t Pbuf[64*ASTRIDE];
  __shared__ __align__(16) half_t Qbuf[64*ASTRIDE];

  int tid = threadIdx.x, lane = tid & 63, wave = tid >> 6;
  int qbase = blockIdx.x * 64;

  for (int i = tid; i < 64*17; i += 512){
    int r = i / 17, c8 = i - r*17;
    *(uint4*)&Abuf[r*ASTRIDE + (c8 << 3)] =
        *(const uint4*)&Ain[(size_t)(qbase + r)*ASTRIDE + (c8 << 3)];
  }
  __syncthreads();

  int rowbase  = (wave >> 2) * 32;
  int colq     = wave & 3;
  int colbase  = colq * 32;
  int tcolbase = colq * 2;
  v4f acc[2][2];
  v4f accd[2][1];

  const half_t* wt0 = wt;
  const half_t* wt1 = wt + 16384;
  const half_t* wt2 = wt + 32768;
  const half_t* wt3 = wt + 65536;
  const half_t* wtf = wt + 81920;
  const half_t* wtd = wt + 98304;

#define ZACC22() { for (int g_ = 0; g_ < 2; g_++) for (int t_ = 0; t_ < 2; t_++) \
                   for (int e_ = 0; e_ < 4; e_++) acc[g_][t_][e_] = 0.f; }

  // L0: A @ W0 -> P (relu)
  ZACC22();
  mfma_pl<4,2>(Abuf, ASTRIDE, rowbase, wt0, 8, 0, tcolbase, acc, lane);
  epilogue64<2>(acc, Pbuf, rowbase, colbase, b0, true, lane);
  __syncthreads();

  // L1: P @ W1 -> Q (relu)
  ZACC22();
  mfma_pl<4,2>(Pbuf, ASTRIDE, rowbase, wt1, 8, 0, tcolbase, acc, lane);
  epilogue64<2>(acc, Qbuf, rowbase, colbase, b1, true, lane);
  __syncthreads();

  // L2: [input_xyz | h1] @ W2 -> P (relu)   (K = 256)
  ZACC22();
  mfma_pl<4,2>(Abuf, ASTRIDE, rowbase, wt2, 8, 0, tcolbase, acc, lane);
  mfma_pl<4,2>(Qbuf, ASTRIDE, rowbase, wt2, 8, 4, tcolbase, acc, lane);
  epilogue64<2>(acc, Pbuf, rowbase, colbase, b2, true, lane);
  __syncthreads();

  // L3: P @ W3 -> A (h3, kept for sigma; input_xyz dead)
  ZACC22();
  mfma_pl<4,2>(Pbuf, ASTRIDE, rowbase, wt3, 8, 0, tcolbase, acc, lane);
  epilogue64<2>(acc, Abuf, rowbase, colbase, b3, true, lane);
  __syncthreads();

  // Wf: A(h3) @ Wf -> P (no relu)
  ZACC22();
  mfma_pl<4,2>(Abuf, ASTRIDE, rowbase, wtf, 8, 0, tcolbase, acc, lane);
  epilogue64<2>(acc, Pbuf, rowbase, colbase, bfb, false, lane);
  __syncthreads();

  // Wd: [P(final) | Din(dir, straight from global/L2)] @ Wd -> Q[:,0:64]
#pragma unroll
  for (int g_ = 0; g_ < 2; g_++)
#pragma unroll
    for (int e_ = 0; e_ < 4; e_++) accd[g_][0][e_] = 0.f;
  mfma_pl<4,1>(Pbuf, ASTRIDE, rowbase, wtd, 4, 0, colq, accd, lane);
  mfma_pl<1,1>(Din + (size_t)qbase*DSTRIDE, DSTRIDE, rowbase, wtd, 4, 4, colq,
               accd, lane);
  epilogue64<1>(accd, Qbuf, rowbase, colq * 16, bdb, true, lane);
  __syncthreads();

  // Tail: sigma = h3(Abuf).Ws + bs ; rgb = d(Qbuf).Wr + br  (8 thr/query)
  {
    int q = tid >> 3, part = tid & 7;
    float s = 0.f;
#pragma unroll
    for (int k = 0; k < 16; k++){
      int kk = part*16 + k;
      s = fmaf((float)Abuf[q*ASTRIDE + kk], Wsb[kk], s);
    }
    s += __shfl_xor(s, 1, 64); s += __shfl_xor(s, 2, 64); s += __shfl_xor(s, 4, 64);

    float r3[3];
#pragma unroll
    for (int c2 = 0; c2 < 3; c2++){
      float rv = 0.f;
#pragma unroll
      for (int k = 0; k < 8; k++){
        int kk = part*8 + k;
        rv = fmaf((float)Qbuf[q*ASTRIDE + kk], Wrb[kk*3 + c2], rv);
      }
      rv += __shfl_xor(rv, 1, 64); rv += __shfl_xor(rv, 2, 64); rv += __shfl_xor(rv, 4, 64);
      r3[c2] = rv;
    }
    if (part == 0){
      size_t ob = ((size_t)(qbase + q)) * 4;
      out[ob + 0] = r3[0] + brb[0];
      out[ob + 1] = r3[1] + brb[1];
      out[ob + 2] = r3[2] + brb[2];
      out[ob + 3] = s + bsb[0];
    }
  }
}

// ---------------------------------------------------------------------------
extern "C" void kernel_launch(void* const* d_in, const int* in_sizes, int n_in,
                              void* d_out, int out_size, void* d_ws, size_t ws_size,
                              hipStream_t stream){
  (void)in_sizes; (void)n_in; (void)out_size; (void)ws_size;

  const int*   indices = (const int*)d_in[0];
  const float* qpts    = (const float*)d_in[1];
  const float* xyzdir  = (const float*)d_in[2];
  const float* cpos    = (const float*)d_in[3];
  const float* codes   = (const float*)d_in[4];
  const float* W0 = (const float*)d_in[5];
  const float* b0 = (const float*)d_in[6];
  const float* W1 = (const float*)d_in[7];
  const float* b1 = (const float*)d_in[8];
  const float* W2 = (const float*)d_in[9];
  const float* b2 = (const float*)d_in[10];
  const float* W3 = (const float*)d_in[11];
  const float* b3 = (const float*)d_in[12];
  const float* Wf = (const float*)d_in[13];
  const float* bf = (const float*)d_in[14];
  const float* Wd = (const float*)d_in[15];
  const float* bd = (const float*)d_in[16];
  const float* Ws = (const float*)d_in[17];
  const float* bs = (const float*)d_in[18];
  const float* Wr = (const float*)d_in[19];
  const float* br = (const float*)d_in[20];

  // ws layout (16-B aligned): Ain | Din | wt | cpos4
  half_t* Ain   = (half_t*)d_ws;                                   // 17,825,792 B
  half_t* Din   = (half_t*)((char*)d_ws + 17825792);               //  5,242,880 B
  half_t* wt    = (half_t*)((char*)d_ws + 17825792 + 5242880);     //    217,088 B
  float4* cpos4 = (float4*)((char*)d_ws + 17825792 + 5242880 + 217088);

  wtrans_kernel<<<(110592 + 255)/256, 256, 0, stream>>>(W0, W1, W2, W3, Wf, Wd,
                                                        indices, cpos, wt, cpos4);
  knn_kernel<<<N_Q/8, 512, 0, stream>>>(indices, qpts, cpos4, codes, xyzdir,
                                        Ain, Din);
  mlp_mfma<<<N_Q/64, 512, 0, stream>>>(Ain, Din, wt,
                                       b0, b1, b2, b3, bf, bd, Ws, bs, Wr, br,
                                       (float*)d_out);
}